// Round 4
// baseline (463.040 us; speedup 1.0000x reference)
//
#include <hip/hip_runtime.h>
#include <hip/hip_bf16.h>

// Gumbel 2:4 masked linear:  out = x @ (W * mask)^T + bias
// Round 6: faithful m201 8-phase port. Per phase: {ds-read fresh subtile |
// stage 1 half-tile | [lgkm(8) if 12 reads] | barrier | lgkmcnt(0) |
// sched_barrier(0) | setprio(1) 16xMFMA setprio(0) | barrier}.
// vmcnt(6) ONLY at phases 4 and 8 (the per-phase vmcnt of R5 re-lockstepped
// the waves and killed cross-wave LDS/MFMA overlap). Single A/B register set,
// same-phase reads, snake (0,0)(0,1)(1,1)(1,0). Stage conveyor re-derived:
// all stage->read distances covered by the ph4/ph8 vmcnt(6) + barrier.

#define K_DIM 4096
#define N_DIM 4096
#define M_DIM 4096

typedef unsigned short ushort_t;
typedef __attribute__((ext_vector_type(8))) __bf16 bf16x8;
typedef __attribute__((ext_vector_type(4))) float floatx4;

__device__ __forceinline__ unsigned f2bf(float f) {
    union { float f; unsigned u; } v; v.f = f;
    unsigned u = v.u;
    return (u + 0x7fffu + ((u >> 16) & 1u)) >> 16;   // RNE
}

// patterns packed 4 bits each, idx0 at bits[3:0]: bit i = pattern[idx][i]
#define PAT_PACKED 0x3596ACu

// ---------------- prep A: x fp32 -> bf16 ----------------
__global__ __launch_bounds__(256) void xcvt_kernel(
    const float4* __restrict__ x4, uint4* __restrict__ xq4) {
    int t = blockIdx.x * 256 + threadIdx.x;
    float4 a = x4[2 * t], b = x4[2 * t + 1];
    uint4 o;
    o.x = f2bf(a.x) | (f2bf(a.y) << 16);
    o.y = f2bf(a.z) | (f2bf(a.w) << 16);
    o.z = f2bf(b.x) | (f2bf(b.y) << 16);
    o.w = f2bf(b.z) | (f2bf(b.w) << 16);
    xq4[t] = o;
}

// ---------------- prep B: gumbel argmax -> masked W -> bf16 ----------------
__global__ __launch_bounds__(256) void mask_kernel(
    const float4* __restrict__ w4, const float4* __restrict__ cw4,
    const float4* __restrict__ gn4, uint2* __restrict__ wq2) {
    __shared__ float lsum[6144];                     // 1024 blocks x 6 logits = 24KB
    const int tid = threadIdx.x;
    const int bb = blockIdx.x;                       // [0,4096)
    const float4* g4 = gn4 + (size_t)bb * 1536;
    const float4* c4 = cw4 + (size_t)bb * 1536;
    float4* l4 = (float4*)lsum;
#pragma unroll
    for (int j = 0; j < 6; j++) {                    // coalesced float4
        float4 g = g4[j * 256 + tid], c = c4[j * 256 + tid];
        float4 s;
        s.x = g.x + c.x; s.y = g.y + c.y; s.z = g.z + c.z; s.w = g.w + c.w;
        l4[j * 256 + tid] = s;
    }
    __syncthreads();

#pragma unroll
    for (int sub = 0; sub < 4; sub++) {
        const int pb = sub * 256 + tid;              // local pattern-block
        const float2* lp = (const float2*)&lsum[pb * 6];
        float2 v0 = lp[0], v1 = lp[1], v2 = lp[2];
        float v[6] = {v0.x, v0.y, v1.x, v1.y, v2.x, v2.y};
        int idx = 0; float m = v[0];
#pragma unroll
        for (int i = 1; i < 6; i++)                  // strict > : first-max
            if (v[i] > m) { m = v[i]; idx = i; }
        const unsigned p = (PAT_PACKED >> (idx * 4)) & 0xF;
        const float4 w = w4[(size_t)bb * 1024 + pb];
        uint2 o;
        o.x = ((p & 1) ? f2bf(w.x) : 0u) | (((p >> 1) & 1) ? (f2bf(w.y) << 16) : 0u);
        o.y = (((p >> 2) & 1) ? f2bf(w.z) : 0u) | (((p >> 3) & 1) ? (f2bf(w.w) << 16) : 0u);
        wq2[(size_t)bb * 1024 + pb] = o;
    }
}

// ---------------- bf16 GEMM, C = A * B^T + bias, m201 8-phase ----------------
// 256x256 tile, 512 thr (8 waves 2M x 4N), per-wave C = 128x64. BK=64.
// LDS 128KB: {A,B} x {buf0,buf1} x {half0,half1}, region = 128 rows x 64k = 16KB.
// Stage conveyor (iter I, t=2I; 1 half-tile per phase = 2 global_load_lds):
//  ph1: buf1.Bh0(t+1)  ph2: buf0.Ah0(t+2)  ph3: buf0.Bh1(t+2)  ph4: buf0.Ah1(t+2)
//  ph5: buf0.Bh0(t+2)  ph6: buf1.Ah0(t+3)  ph7: buf1.Bh1(t+3)  ph8: buf1.Ah1(t+3)
// vmcnt(6) at ph4/ph8 leaves the 3 newest stages in flight => everything
// older has landed; the phase's closing barrier publishes. Reads at ph_k are
// drained by ph_k's own lgkmcnt(0) before MFMA, so the following stage may
// overwrite. Chunk swizzle: LDS slot c of row lr holds global chunk c^(lr&7),
// applied inverse on the global source (global_load_lds dest lane-linear).

#define BK 64

__device__ __forceinline__ void async16(const ushort_t* g, ushort_t* l) {
    __builtin_amdgcn_global_load_lds(
        (const __attribute__((address_space(1))) void*)g,
        (__attribute__((address_space(3))) void*)l, 16, 0, 0);
}

__global__ __launch_bounds__(512, 2) void gemm_bt_kernel(
    const ushort_t* __restrict__ A,   // M x K bf16 (x)
    const ushort_t* __restrict__ B,   // N x K bf16 (masked W)
    const float* __restrict__ bias,
    float* __restrict__ C) {
    __shared__ ushort_t As[32768];    // 64KB
    __shared__ ushort_t Bs[32768];    // 64KB

    const int tid  = threadIdx.x;
    const int lane = tid & 63;
    const int wave = tid >> 6;
    const int wm   = wave >> 2;       // 0..1
    const int wn   = wave & 3;        // 0..3
    const int fr   = lane & 15;
    const int q    = lane >> 4;
    const int f7   = fr & 7;

    // XCD-chunked swizzle: 256 blocks, 32 contiguous per XCD
    const int fid = blockIdx.y * 16 + blockIdx.x;
    const int swz = (fid & 7) * 32 + (fid >> 3);
    const int bm  = (swz >> 4) * 256;
    const int bn  = (swz & 15) * 256;

    // staging: slot s = j*512+tid, lr = s>>3, c = s&7; holds global chunk c^(lr&7)
    const int u  = tid >> 3;
    const int cs = (tid & 7) ^ (u & 7);
    const ushort_t* Abase = A + (size_t)(bm + u) * K_DIM + cs * 8;
    const ushort_t* Bbase = B + (size_t)(bn + (u & 31) + ((u >> 5) << 6)) * K_DIM + cs * 8;
    ushort_t* lAd = &As[tid * 8];
    ushort_t* lBd = &Bs[tid * 8];

    // read offsets (ushort units)
    const int aOff = wm * 4096 + fr * 64;
    const int bOff = wn * 2048 + fr * 64;
    const int c0   = (q ^ f7) * 8;
    const int c1   = ((4 + q) ^ f7) * 8;

    bf16x8 aR[4][2], bR[2][2];
    floatx4 acc[8][4] = {};

#define STA(db_, h_, t_) do {                                                   \
        async16(Abase + (size_t)((h_) * 64      ) * K_DIM + (size_t)(t_) * BK,  \
                lAd + (db_) * 16384 + (h_) * 8192);                             \
        async16(Abase + (size_t)((h_) * 64 + 128) * K_DIM + (size_t)(t_) * BK,  \
                lAd + (db_) * 16384 + (h_) * 8192 + 4096);                      \
    } while (0)
#define STB(db_, h_, t_) do {                                                   \
        async16(Bbase + (size_t)((h_) * 32      ) * K_DIM + (size_t)(t_) * BK,  \
                lBd + (db_) * 16384 + (h_) * 8192);                             \
        async16(Bbase + (size_t)((h_) * 32 + 128) * K_DIM + (size_t)(t_) * BK,  \
                lBd + (db_) * 16384 + (h_) * 8192 + 4096);                      \
    } while (0)

#define LDA_S(db_, qm_) do {                                                    \
        _Pragma("unroll")                                                       \
        for (int r = 0; r < 4; ++r) {                                           \
            const int o = (db_) * 16384 + (qm_) * 8192 + aOff + r * 1024;       \
            aR[r][0] = *(const bf16x8*)&As[o + c0];                             \
            aR[r][1] = *(const bf16x8*)&As[o + c1];                             \
        } } while (0)
#define LDB_S(db_, h_) do {                                                     \
        _Pragma("unroll")                                                       \
        for (int c = 0; c < 2; ++c) {                                           \
            const int o = (db_) * 16384 + (h_) * 8192 + bOff + c * 1024;        \
            bR[c][0] = *(const bf16x8*)&Bs[o + c0];                             \
            bR[c][1] = *(const bf16x8*)&Bs[o + c1];                             \
        } } while (0)

#define MMQ(qm_, qn_) do {                                                      \
        __builtin_amdgcn_s_setprio(1);                                          \
        _Pragma("unroll")                                                       \
        for (int kh = 0; kh < 2; ++kh)                                          \
            _Pragma("unroll")                                                   \
            for (int r = 0; r < 4; ++r)                                         \
                _Pragma("unroll")                                               \
                for (int c = 0; c < 2; ++c)                                     \
                    acc[(qm_) * 4 + r][(qn_) * 2 + c] =                         \
                        __builtin_amdgcn_mfma_f32_16x16x32_bf16(                \
                            aR[r][kh], bR[c][kh],                               \
                            acc[(qm_) * 4 + r][(qn_) * 2 + c], 0, 0, 0);        \
        __builtin_amdgcn_s_setprio(0);                                          \
    } while (0)

#define BAR  __builtin_amdgcn_s_barrier()
#define LGK(N_) asm volatile("s_waitcnt lgkmcnt(" #N_ ")" ::: "memory")
#define VMW(N_) asm volatile("s_waitcnt vmcnt(" #N_ ")" ::: "memory")
#define SB   __builtin_amdgcn_sched_barrier(0)

    // prologue: buf0 all 4 halves (t=0) + buf1.{Ah0,Bh1,Ah1} (t=1); drain buf0
    STA(0, 0, 0); STB(0, 0, 0); STB(0, 1, 0); STA(0, 1, 0);
    STA(1, 0, 1); STB(1, 1, 1); STA(1, 1, 1);
    VMW(6);                               // buf0's 8 loads landed; buf1's 6 in flight
    BAR;

#pragma unroll 1
    for (int I = 0; I < 31; ++I) {
        const int t1 = 2 * I + 1, t2 = 2 * I + 2, t3 = 2 * I + 3;
        // ph1 (0,0): fresh Ah0+Bh0 (12 reads)
        LDA_S(0, 0); LDB_S(0, 0); STB(1, 0, t1); LGK(8);
        BAR; LGK(0); SB; MMQ(0, 0); BAR;
        // ph2 (0,1): fresh Bh1 (4)
        LDB_S(0, 1); STA(0, 0, t2);
        BAR; LGK(0); SB; MMQ(0, 1); BAR;
        // ph3 (1,1): fresh Ah1 (8)
        LDA_S(0, 1); STB(0, 1, t2);
        BAR; LGK(0); SB; MMQ(1, 1); BAR;
        // ph4 (1,0): fresh Bh0 (4); K-tile vmcnt checkpoint
        LDB_S(0, 0); STA(0, 1, t2); VMW(6);
        BAR; LGK(0); SB; MMQ(1, 0); BAR;
        // ph5 (0,0) on buf1: fresh Ah0+Bh0 (12)
        LDA_S(1, 0); LDB_S(1, 0); STB(0, 0, t2); LGK(8);
        BAR; LGK(0); SB; MMQ(0, 0); BAR;
        // ph6 (0,1): fresh Bh1 (4)
        LDB_S(1, 1); STA(1, 0, t3);
        BAR; LGK(0); SB; MMQ(0, 1); BAR;
        // ph7 (1,1): fresh Ah1 (8)
        LDA_S(1, 1); STB(1, 1, t3);
        BAR; LGK(0); SB; MMQ(1, 1); BAR;
        // ph8 (1,0): fresh Bh0 (4); K-tile vmcnt checkpoint
        LDB_S(1, 0); STA(1, 1, t3); VMW(6);
        BAR; LGK(0); SB; MMQ(1, 0); BAR;
    }
    // peeled final iteration (tiles 62 in buf0, 63 in buf1)
    LDA_S(0, 0); LDB_S(0, 0); STB(1, 0, 63); LGK(8);
    BAR; LGK(0); SB; MMQ(0, 0); BAR;
    LDB_S(0, 1);
    BAR; LGK(0); SB; MMQ(0, 1); BAR;
    LDA_S(0, 1);
    BAR; LGK(0); SB; MMQ(1, 1); BAR;
    LDB_S(0, 0); VMW(0);                  // drain the ph1 stage for ph5/ph8 reads
    BAR; LGK(0); SB; MMQ(1, 0); BAR;
    LDA_S(1, 0); LDB_S(1, 0); LGK(8);
    BAR; LGK(0); SB; MMQ(0, 0); BAR;
    LDB_S(1, 1);
    BAR; LGK(0); SB; MMQ(0, 1); BAR;
    LDA_S(1, 1);
    BAR; LGK(0); SB; MMQ(1, 1); BAR;
    LDB_S(1, 0);
    BAR; LGK(0); SB; MMQ(1, 0);

#undef STA
#undef STB
#undef LDA_S
#undef LDB_S
#undef MMQ
#undef BAR
#undef LGK
#undef VMW
#undef SB

    // epilogue: D col = lane&15, row = q*4 + reg (verified mapping)
#pragma unroll
    for (int c = 0; c < 4; ++c) {
        const int gcol = bn + wn * 64 + c * 16 + fr;
        const float bv = bias[gcol];
#pragma unroll
        for (int r = 0; r < 8; ++r) {
            const int grow = bm + wm * 128 + r * 16 + q * 4;
#pragma unroll
            for (int reg = 0; reg < 4; ++reg)
                C[(size_t)(grow + reg) * N_DIM + gcol] = acc[r][c][reg] + bv;
        }
    }
}

extern "C" void kernel_launch(void* const* d_in, const int* in_sizes, int n_in,
                              void* d_out, int out_size, void* d_ws, size_t ws_size,
                              hipStream_t stream) {
    const float* x    = (const float*)d_in[0];
    const float* w    = (const float*)d_in[1];
    const float* bias = (const float*)d_in[2];
    const float* cw   = (const float*)d_in[3];
    const float* gn   = (const float*)d_in[4];
    ushort_t* xq = (ushort_t*)d_ws;                       // 32 MiB
    ushort_t* wq = xq + (size_t)M_DIM * K_DIM;            // 32 MiB
    float* out = (float*)d_out;

    xcvt_kernel<<<8192, 256, 0, stream>>>((const float4*)x, (uint4*)xq);
    mask_kernel<<<4096, 256, 0, stream>>>(
        (const float4*)w, (const float4*)cw, (const float4*)gn, (uint2*)wq);
    dim3 grid(N_DIM / 256, M_DIM / 256);
    gemm_bt_kernel<<<grid, 512, 0, stream>>>(xq, wq, bias, out);
}

// Round 5
// 434.793 us; speedup vs baseline: 1.0650x; 1.0650x over previous
//
#include <hip/hip_runtime.h>
#include <hip/hip_bf16.h>

// Gumbel 2:4 masked linear:  out = x @ (W * mask)^T + bias
// Round 7: R3 (look-ahead register pipeline, measured best 142us) with the
// stage conveyor re-derived for 4 counted-vmcnt checkpoints per 8 phases
// (VMW(8)@ph3, VMW(8)@ph4, VMW(8)@ph7, VMW(4)@ph8) instead of R3's
// per-phase VMW(6). Stages: ph1={buf1.Ah1,Bh1}(t+1), ph2=buf0.Ah0(t+2),
// ph3=buf0.Bh0(t+2), ph4={buf0.Ah1,Bh1}(t+2), ph6=buf1.Ah0(t+3),
// ph7=buf1.Bh0(t+3). Derivation invariants (verified per region):
//   overwrite at phase p requires p >= last_read + 2  (all exact or slack)
//   read at phase r requires checkpoint c <= r-1 with stage landed at c
// Reads/LGK pacing/swizzle/epilogue identical to R3.

#define K_DIM 4096
#define N_DIM 4096
#define M_DIM 4096

typedef unsigned short ushort_t;
typedef __attribute__((ext_vector_type(8))) __bf16 bf16x8;
typedef __attribute__((ext_vector_type(4))) float floatx4;

__device__ __forceinline__ unsigned f2bf(float f) {
    union { float f; unsigned u; } v; v.f = f;
    unsigned u = v.u;
    return (u + 0x7fffu + ((u >> 16) & 1u)) >> 16;   // RNE
}

// patterns packed 4 bits each, idx0 at bits[3:0]: bit i = pattern[idx][i]
#define PAT_PACKED 0x3596ACu

// ---------------- prep A: x fp32 -> bf16 ----------------
__global__ __launch_bounds__(256) void xcvt_kernel(
    const float4* __restrict__ x4, uint4* __restrict__ xq4) {
    int t = blockIdx.x * 256 + threadIdx.x;
    float4 a = x4[2 * t], b = x4[2 * t + 1];
    uint4 o;
    o.x = f2bf(a.x) | (f2bf(a.y) << 16);
    o.y = f2bf(a.z) | (f2bf(a.w) << 16);
    o.z = f2bf(b.x) | (f2bf(b.y) << 16);
    o.w = f2bf(b.z) | (f2bf(b.w) << 16);
    xq4[t] = o;
}

// ---------------- prep B: gumbel argmax -> masked W -> bf16 ----------------
__global__ __launch_bounds__(256) void mask_kernel(
    const float4* __restrict__ w4, const float4* __restrict__ cw4,
    const float4* __restrict__ gn4, uint2* __restrict__ wq2) {
    __shared__ float lsum[6144];                     // 1024 blocks x 6 logits = 24KB
    const int tid = threadIdx.x;
    const int bb = blockIdx.x;                       // [0,4096)
    const float4* g4 = gn4 + (size_t)bb * 1536;
    const float4* c4 = cw4 + (size_t)bb * 1536;
    float4* l4 = (float4*)lsum;
#pragma unroll
    for (int j = 0; j < 6; j++) {                    // coalesced float4
        float4 g = g4[j * 256 + tid], c = c4[j * 256 + tid];
        float4 s;
        s.x = g.x + c.x; s.y = g.y + c.y; s.z = g.z + c.z; s.w = g.w + c.w;
        l4[j * 256 + tid] = s;
    }
    __syncthreads();

#pragma unroll
    for (int sub = 0; sub < 4; sub++) {
        const int pb = sub * 256 + tid;              // local pattern-block
        const float2* lp = (const float2*)&lsum[pb * 6];
        float2 v0 = lp[0], v1 = lp[1], v2 = lp[2];
        float v[6] = {v0.x, v0.y, v1.x, v1.y, v2.x, v2.y};
        int idx = 0; float m = v[0];
#pragma unroll
        for (int i = 1; i < 6; i++)                  // strict > : first-max
            if (v[i] > m) { m = v[i]; idx = i; }
        const unsigned p = (PAT_PACKED >> (idx * 4)) & 0xF;
        const float4 w = w4[(size_t)bb * 1024 + pb];
        uint2 o;
        o.x = ((p & 1) ? f2bf(w.x) : 0u) | (((p >> 1) & 1) ? (f2bf(w.y) << 16) : 0u);
        o.y = (((p >> 2) & 1) ? f2bf(w.z) : 0u) | (((p >> 3) & 1) ? (f2bf(w.w) << 16) : 0u);
        wq2[(size_t)bb * 1024 + pb] = o;
    }
}

// ---------------- bf16 GEMM, C = A * B^T + bias ----------------
// 256x256 tile, 512 thr (8 waves 2M x 4N), per-wave C = 128x64. BK=64,
// 2 K-tiles resident (buf0/buf1, 4 half-regions each, 16KB per region).
//
// Phase table (steady iter I, t=2I; LD feeds MFMA of NEXT phase):
//  ph | LD (ds_read)              | STAGE               | VMW  | lgkm | MFMA
//   1 | a1<-buf0.Ah1   [8]        | b1.Ah1,b1.Bh1 (t+1) |  --  |  8   | (0,0) a0,b0
//   2 | b1<-buf0.Bh1   [4]        | b0.Ah0 (t+2)        |  --  |  4   | (1,0) a1,b0
//   3 | --                        | b0.Bh0 (t+2)        |  8   |  0   | (1,1) a1,b1
//   4 | a1<-b1.Ah0,b0<-b1.Bh0 [12]| b0.Ah1,b0.Bh1 (t+2) |  8   |  12  | (0,1) a0,b1
//   5 | a0<-buf1.Ah1   [8]        | --                  |  --  |  8   | (0,0) a1,b0
//   6 | b1<-buf1.Bh1   [4]        | b1.Ah0 (t+3)        |  --  |  4   | (1,0) a0,b0
//   7 | --                        | b1.Bh0 (t+3)        |  8   |  0   | (1,1) a0,b1
//   8 | a0<-b0.Ah0,b0<-b0.Bh0 [12]| --                  |  4   |  12  | (0,1) a1,b1
// Checkpoint certifications (loads after certified point = VMW value):
//  ph3 VMW(8): stages <= prev ph7 landed (ph1:4+ph2:2+ph3:2 in flight)
//              -> ph4's reads of buf1.Ah0/Bh0 safe.
//  ph4 VMW(8): stages <= ph1 landed (ph2:2+ph3:2+ph4:4) -> ph5/ph6 reads safe.
//  ph7 VMW(8): stages <= ph3 landed (ph4:4+ph6:2+ph7:2) -> ph8 reads safe.
//  ph8 VMW(4): stages <= ph4 landed (ph6:2+ph7:2) -> next ph1/ph2 reads safe.
// Overwrite >= last_read+2 for all 8 regions (checked).
// Chunk swizzle: LDS slot c of row lr holds global chunk c ^ (lr&7), applied
// inverse on the global source (global_load_lds dest lane-linear).

#define BK 64

__device__ __forceinline__ void async16(const ushort_t* g, ushort_t* l) {
    __builtin_amdgcn_global_load_lds(
        (const __attribute__((address_space(1))) void*)g,
        (__attribute__((address_space(3))) void*)l, 16, 0, 0);
}

__global__ __launch_bounds__(512, 2) void gemm_bt_kernel(
    const ushort_t* __restrict__ A,   // M x K bf16 (x)
    const ushort_t* __restrict__ B,   // N x K bf16 (masked W)
    const float* __restrict__ bias,
    float* __restrict__ C) {
    __shared__ ushort_t As[32768];    // 64KB
    __shared__ ushort_t Bs[32768];    // 64KB

    const int tid  = threadIdx.x;
    const int lane = tid & 63;
    const int wave = tid >> 6;
    const int wm   = wave >> 2;       // 0..1
    const int wn   = wave & 3;        // 0..3
    const int fr   = lane & 15;
    const int q    = lane >> 4;
    const int f7   = fr & 7;

    // XCD-chunked swizzle: 256 blocks, 32 contiguous per XCD
    const int fid = blockIdx.y * 16 + blockIdx.x;
    const int swz = (fid & 7) * 32 + (fid >> 3);
    const int bm  = (swz >> 4) * 256;
    const int bn  = (swz & 15) * 256;

    // staging: slot s = j*512+tid, lr = s>>3, c = s&7; holds global chunk c^(lr&7)
    const int u  = tid >> 3;
    const int cs = (tid & 7) ^ (u & 7);
    const ushort_t* Abase = A + (size_t)(bm + u) * K_DIM + cs * 8;
    const ushort_t* Bbase = B + (size_t)(bn + (u & 31) + ((u >> 5) << 6)) * K_DIM + cs * 8;
    ushort_t* lAd = &As[tid * 8];
    ushort_t* lBd = &Bs[tid * 8];

    // read offsets (ushort units)
    const int aOff = wm * 4096 + fr * 64;
    const int bOff = wn * 2048 + fr * 64;
    const int c0   = (q ^ f7) * 8;
    const int c1   = ((4 + q) ^ f7) * 8;

    bf16x8 a0[4][2], a1[4][2], b0[2][2], b1[2][2];
    floatx4 acc[8][4] = {};

#define STA(db_, h_, t_) do {                                                   \
        async16(Abase + (size_t)((h_) * 64      ) * K_DIM + (size_t)(t_) * BK,  \
                lAd + (db_) * 16384 + (h_) * 8192);                             \
        async16(Abase + (size_t)((h_) * 64 + 128) * K_DIM + (size_t)(t_) * BK,  \
                lAd + (db_) * 16384 + (h_) * 8192 + 4096);                      \
    } while (0)
#define STB(db_, h_, t_) do {                                                   \
        async16(Bbase + (size_t)((h_) * 32      ) * K_DIM + (size_t)(t_) * BK,  \
                lBd + (db_) * 16384 + (h_) * 8192);                             \
        async16(Bbase + (size_t)((h_) * 32 + 128) * K_DIM + (size_t)(t_) * BK,  \
                lBd + (db_) * 16384 + (h_) * 8192 + 4096);                      \
    } while (0)

#define LDA_S(dst_, db_, qm_) do {                                              \
        _Pragma("unroll")                                                       \
        for (int r = 0; r < 4; ++r) {                                           \
            const int o = (db_) * 16384 + (qm_) * 8192 + aOff + r * 1024;       \
            dst_[r][0] = *(const bf16x8*)&As[o + c0];                           \
            dst_[r][1] = *(const bf16x8*)&As[o + c1];                           \
        } } while (0)
#define LDB_S(dst_, db_, h_) do {                                               \
        _Pragma("unroll")                                                       \
        for (int c = 0; c < 2; ++c) {                                           \
            const int o = (db_) * 16384 + (h_) * 8192 + bOff + c * 1024;        \
            dst_[c][0] = *(const bf16x8*)&Bs[o + c0];                           \
            dst_[c][1] = *(const bf16x8*)&Bs[o + c1];                           \
        } } while (0)

#define MMQ(qm_, qn_, A_, B_) do {                                              \
        __builtin_amdgcn_s_setprio(1);                                          \
        _Pragma("unroll")                                                       \
        for (int kh = 0; kh < 2; ++kh)                                          \
            _Pragma("unroll")                                                   \
            for (int r = 0; r < 4; ++r)                                         \
                _Pragma("unroll")                                               \
                for (int c = 0; c < 2; ++c)                                     \
                    acc[(qm_) * 4 + r][(qn_) * 2 + c] =                         \
                        __builtin_amdgcn_mfma_f32_16x16x32_bf16(                \
                            A_[r][kh], B_[c][kh],                               \
                            acc[(qm_) * 4 + r][(qn_) * 2 + c], 0, 0, 0);        \
        __builtin_amdgcn_s_setprio(0);                                          \
    } while (0)

#define VMW(N_) asm volatile("s_waitcnt vmcnt(" #N_ ")" ::: "memory")
#define SO(N_) do {                                                             \
        __builtin_amdgcn_sched_barrier(0);                                      \
        __builtin_amdgcn_s_barrier();                                           \
        asm volatile("s_waitcnt lgkmcnt(" #N_ ")" ::: "memory");                \
        __builtin_amdgcn_sched_barrier(0);                                      \
    } while (0)
#define PE do {                                                                 \
        __builtin_amdgcn_sched_barrier(0);                                      \
        __builtin_amdgcn_s_barrier();                                           \
    } while (0)

    // prologue: buf0 all 4 halves (t=0) + buf1.{Ah0,Bh0} (t=1)
    STA(0, 0, 0); STB(0, 0, 0); STA(0, 1, 0); STB(0, 1, 0);
    STA(1, 0, 1); STB(1, 0, 1);
    VMW(4);                               // buf0's 8 loads landed; buf1 pair in flight
    __builtin_amdgcn_sched_barrier(0);
    __builtin_amdgcn_s_barrier();
    LDA_S(a0, 0, 0); LDB_S(b0, 0, 0);     // 12 reads; paced by ph1's lgkm(8)

#pragma unroll 1
    for (int I = 0; I < 31; ++I) {
        const int t1 = 2 * I + 1, t2 = 2 * I + 2, t3 = 2 * I + 3;
        LDA_S(a1, 0, 1);                  STA(1, 1, t1); STB(1, 1, t1);
                                          SO(8);  MMQ(0, 0, a0, b0); PE;
        LDB_S(b1, 0, 1);                  STA(0, 0, t2);
                                          SO(4);  MMQ(1, 0, a1, b0); PE;
                                          STB(0, 0, t2); VMW(8);
                                          SO(0);  MMQ(1, 1, a1, b1); PE;
        LDA_S(a1, 1, 0); LDB_S(b0, 1, 0); STA(0, 1, t2); STB(0, 1, t2); VMW(8);
                                          SO(12); MMQ(0, 1, a0, b1); PE;
        LDA_S(a0, 1, 1);
                                          SO(8);  MMQ(0, 0, a1, b0); PE;
        LDB_S(b1, 1, 1);                  STA(1, 0, t3);
                                          SO(4);  MMQ(1, 0, a0, b0); PE;
                                          STB(1, 0, t3); VMW(8);
                                          SO(0);  MMQ(1, 1, a0, b1); PE;
        LDA_S(a0, 0, 0); LDB_S(b0, 0, 0); VMW(4);
                                          SO(12); MMQ(0, 1, a1, b1); PE;
    }
    // peeled final iteration (tiles 62 in buf0, 63 in buf1)
    LDA_S(a1, 0, 1);                  STA(1, 1, 63); STB(1, 1, 63);
                                      SO(8);  MMQ(0, 0, a0, b0); PE;
    LDB_S(b1, 0, 1);
                                      SO(4);  MMQ(1, 0, a1, b0); PE;
                                      VMW(4);  // iter-30 ph6/7 stages landed
                                      SO(0);  MMQ(1, 1, a1, b1); PE;
    LDA_S(a1, 1, 0); LDB_S(b0, 1, 0); VMW(0);  // peel-ph1 stages landed
                                      SO(12); MMQ(0, 1, a0, b1); PE;
    LDA_S(a0, 1, 1);
                                      SO(8);  MMQ(0, 0, a1, b0); PE;
    LDB_S(b1, 1, 1);
                                      SO(4);  MMQ(1, 0, a0, b0); PE;
                                      SO(0);  MMQ(1, 1, a0, b1); PE;
                                      SO(0);  MMQ(0, 1, a1, b1);

#undef STA
#undef STB
#undef LDA_S
#undef LDB_S
#undef MMQ
#undef VMW
#undef SO
#undef PE

    // epilogue: D col = lane&15, row = q*4 + reg (verified mapping)
#pragma unroll
    for (int c = 0; c < 4; ++c) {
        const int gcol = bn + wn * 64 + c * 16 + fr;
        const float bv = bias[gcol];
#pragma unroll
        for (int r = 0; r < 8; ++r) {
            const int grow = bm + wm * 128 + r * 16 + q * 4;
#pragma unroll
            for (int reg = 0; reg < 4; ++reg)
                C[(size_t)(grow + reg) * N_DIM + gcol] = acc[r][c][reg] + bv;
        }
    }
}

extern "C" void kernel_launch(void* const* d_in, const int* in_sizes, int n_in,
                              void* d_out, int out_size, void* d_ws, size_t ws_size,
                              hipStream_t stream) {
    const float* x    = (const float*)d_in[0];
    const float* w    = (const float*)d_in[1];
    const float* bias = (const float*)d_in[2];
    const float* cw   = (const float*)d_in[3];
    const float* gn   = (const float*)d_in[4];
    ushort_t* xq = (ushort_t*)d_ws;                       // 32 MiB
    ushort_t* wq = xq + (size_t)M_DIM * K_DIM;            // 32 MiB
    float* out = (float*)d_out;

    xcvt_kernel<<<8192, 256, 0, stream>>>((const float4*)x, (uint4*)xq);
    mask_kernel<<<4096, 256, 0, stream>>>(
        (const float4*)w, (const float4*)cw, (const float4*)gn, (uint2*)wq);
    dim3 grid(N_DIM / 256, M_DIM / 256);
    gemm_bt_kernel<<<grid, 512, 0, stream>>>(xq, wq, bias, out);
}